// Round 15
// baseline (6890.250 us; speedup 1.0000x reference)
//
#include <hip/hip_runtime.h>
#include <hip/hip_bf16.h>
#include <cstdint>
#include <cstddef>

#define T_TOK 16384
#define DIM   1024
#define HID   4096
#define NE    8
#define NSLOT 34816   /* 32768 + 8*256 max padded slots (256-aligned segments) */
#define BK 32

typedef __bf16 bf16_t;
typedef __bf16 bf16x8 __attribute__((ext_vector_type(8)));
typedef float  f32x4  __attribute__((ext_vector_type(4)));

__device__ __forceinline__ void gload_lds16(const void* g, const void* l) {
  __builtin_amdgcn_global_load_lds(
      (const __attribute__((address_space(1))) uint32_t*)(uintptr_t)g,
      (__attribute__((address_space(3))) uint32_t*)(uint32_t)(uintptr_t)l,
      16, 0, 0);
}

// meta layout (ints): [0..7]=counts, [8..15]=cursor, [16..23]=seg_base

// router + fused: f32->bf16 x conversion, ptok=-1 init, out=bias init,
// cursor zeroing. All consumed only by LATER kernels (boundary-ordered).
__global__ __launch_bounds__(256) void router_kernel(
    const float* __restrict__ x, const float* __restrict__ rw,
    float* __restrict__ logits, int* __restrict__ meta,
    int* __restrict__ te, float* __restrict__ tw, bf16_t* __restrict__ Xb,
    int* __restrict__ ptok, float* __restrict__ out,
    const float* __restrict__ bias) {
  int gi = blockIdx.x * 256 + threadIdx.x;
  if (gi < NSLOT) ptok[gi] = -1;
  if (gi < 8) meta[8 + gi] = 0;
  const int n4 = T_TOK * DIM / 4;
  for (int i = gi; i < n4; i += gridDim.x * 256) {
    ((float4*)out)[i] = ((const float4*)bias)[i & 255];
  }

  const int lane = threadIdx.x & 63;
  const int t = blockIdx.x * 4 + (threadIdx.x >> 6);
  const float* xr = x + (size_t)t * DIM;
  float acc[NE] = {0.f,0.f,0.f,0.f,0.f,0.f,0.f,0.f};
#pragma unroll
  for (int j = 0; j < 2; ++j) {
    int d0 = j * 512 + lane * 8;
    float4 a = *(const float4*)(xr + d0);
    float4 b = *(const float4*)(xr + d0 + 4);
    bf16x8 o = { (bf16_t)a.x, (bf16_t)a.y, (bf16_t)a.z, (bf16_t)a.w,
                 (bf16_t)b.x, (bf16_t)b.y, (bf16_t)b.z, (bf16_t)b.w };
    *(bf16x8*)(Xb + (size_t)t * DIM + d0) = o;
    float xs[8] = {a.x, a.y, a.z, a.w, b.x, b.y, b.z, b.w};
#pragma unroll
    for (int k = 0; k < 8; ++k) {
      float4 wa = *(const float4*)(rw + (size_t)(d0 + k) * NE);
      float4 wb = *(const float4*)(rw + (size_t)(d0 + k) * NE + 4);
      acc[0] += xs[k] * wa.x; acc[1] += xs[k] * wa.y;
      acc[2] += xs[k] * wa.z; acc[3] += xs[k] * wa.w;
      acc[4] += xs[k] * wb.x; acc[5] += xs[k] * wb.y;
      acc[6] += xs[k] * wb.z; acc[7] += xs[k] * wb.w;
    }
  }
#pragma unroll
  for (int off = 32; off; off >>= 1) {
#pragma unroll
    for (int e = 0; e < NE; ++e) acc[e] += __shfl_down(acc[e], off);
  }
  if (lane == 0) {
    float m = acc[0];
#pragma unroll
    for (int e = 1; e < NE; ++e) m = fmaxf(m, acc[e]);
    float p[NE]; float s = 0.f;
#pragma unroll
    for (int e = 0; e < NE; ++e) { p[e] = expf(acc[e] - m); s += p[e]; }
    float inv = 1.0f / s;
    int e0 = 0;
#pragma unroll
    for (int e = 1; e < NE; ++e) if (p[e] > p[e0]) e0 = e;
    int e1 = (e0 == 0) ? 1 : 0;
#pragma unroll
    for (int e = 0; e < NE; ++e) if (e != e0 && p[e] > p[e1]) e1 = e;
#pragma unroll
    for (int e = 0; e < NE; ++e) logits[(size_t)t * NE + e] = acc[e];
    te[2 * t]     = e0;  te[2 * t + 1] = e1;
    tw[2 * t]     = p[e0] * inv;
    tw[2 * t + 1] = p[e1] * inv;
  }
}

// scatter: per-block global histogram + LDS-aggregated cursor atomics
__global__ __launch_bounds__(256) void scatter_kernel(
    const int* __restrict__ te, const float* __restrict__ tw,
    int* __restrict__ meta, int* __restrict__ ptok, float* __restrict__ pw) {
  __shared__ int gcnt[8], sseg[8], gbase[8], lcnt[8];
  const int t0 = threadIdx.x;
  if (t0 < 8) { gcnt[t0] = 0; lcnt[t0] = 0; }
  __syncthreads();
  int h0=0,h1=0,h2=0,h3=0,h4=0,h5=0,h6=0,h7=0;
  for (int i = t0; i < 2 * T_TOK; i += 256) {
    int e = te[i];
    h0 += (e == 0); h1 += (e == 1); h2 += (e == 2); h3 += (e == 3);
    h4 += (e == 4); h5 += (e == 5); h6 += (e == 6); h7 += (e == 7);
  }
  atomicAdd(&gcnt[0], h0); atomicAdd(&gcnt[1], h1);
  atomicAdd(&gcnt[2], h2); atomicAdd(&gcnt[3], h3);
  atomicAdd(&gcnt[4], h4); atomicAdd(&gcnt[5], h5);
  atomicAdd(&gcnt[6], h6); atomicAdd(&gcnt[7], h7);
  __syncthreads();
  if (t0 < 8) {
    int s2 = 0;
#pragma unroll
    for (int e2 = 0; e2 < 8; ++e2) {
      int p = (gcnt[e2] + 255) & ~255;
      s2 += (e2 < t0) ? p : 0;
    }
    sseg[t0] = s2;
    if (blockIdx.x == 0) { meta[t0] = gcnt[t0]; meta[16 + t0] = s2; }
  }
  int t = blockIdx.x * 256 + t0;
  int e0 = te[2 * t], e1 = te[2 * t + 1];
  int lp0 = atomicAdd(&lcnt[e0], 1);
  int lp1 = atomicAdd(&lcnt[e1], 1);
  __syncthreads();
  if (t0 < 8) gbase[t0] = atomicAdd(&meta[8 + t0], lcnt[t0]);
  __syncthreads();
  int pos0 = sseg[e0] + gbase[e0] + lp0;
  int pos1 = sseg[e1] + gbase[e1] + lp1;
  ptok[pos0] = t;  pw[pos0] = tw[2 * t];
  ptok[pos1] = t;  pw[pos1] = tw[2 * t + 1];
}

// LDS-free register transpose tile: src float RxC -> dst bf16 CxR (r12-verified)
__device__ __forceinline__ void tr_tile(const float* __restrict__ s,
                                        bf16_t* __restrict__ d,
                                        int R, int C, int c0, int r0) {
  const int tr = threadIdx.x & 7, tc = threadIdx.x >> 3;
  bf16x8 rows[8];
#pragma unroll
  for (int p = 0; p < 8; ++p) {
    const float* rp = s + (size_t)(r0 + 8 * tr + p) * C + c0 + 8 * tc;
    float4 a = *(const float4*)rp;
    float4 b = *(const float4*)(rp + 4);
    bf16x8 v = { (bf16_t)a.x, (bf16_t)a.y, (bf16_t)a.z, (bf16_t)a.w,
                 (bf16_t)b.x, (bf16_t)b.y, (bf16_t)b.z, (bf16_t)b.w };
    rows[p] = v;
  }
#pragma unroll
  for (int q = 0; q < 8; ++q) {
    bf16x8 o = { rows[0][q], rows[1][q], rows[2][q], rows[3][q],
                 rows[4][q], rows[5][q], rows[6][q], rows[7][q] };
    *(bf16x8*)(d + (size_t)(c0 + 8 * tc + q) * R + r0 + 8 * tr) = o;
  }
}

__global__ __launch_bounds__(256) void transpose_both_kernel(
    const float* __restrict__ w1, const float* __restrict__ w2,
    bf16_t* __restrict__ W1t, bf16_t* __restrict__ W2t) {
  int b = blockIdx.x;
  if (b < 2048) {
    int e = b >> 8, rem = b & 255;
    tr_tile(w1 + (size_t)e * DIM * HID, W1t + (size_t)e * DIM * HID,
            DIM, HID, (rem & 15) * 256, (rem >> 4) * 64);
  } else {
    b -= 2048;
    int e = b >> 8, rem = b & 255;
    tr_tile(w2 + (size_t)e * DIM * HID, W2t + (size_t)e * DIM * HID,
            HID, DIM, (rem & 3) * 256, (rem >> 2) * 64);
  }
}

__global__ __launch_bounds__(256) void transpose_cvt_kernel(
    const float* __restrict__ src, bf16_t* __restrict__ dst, int R, int C) {
  int e = blockIdx.z;
  tr_tile(src + (size_t)e * R * C, dst + (size_t)e * R * C,
          R, C, blockIdx.x * 256, blockIdx.y * 64);
}

// ===== 256x256 BK=32 8-wave DOUBLE-buffered GEMM, 64KB LDS -> 2 blocks/CU =====
// m97-style loop: STAGE(next) -> 12 ds_read -> 32 MFMA -> __syncthreads().
// No inline asm (compiler emits fine-grained waitcnts; m97 evidence).
// LDS: buf p at p*32768 {A 256x32 bf16 16KB, B at +16384}. Row = 64B = 4 chunks.
// Swizzle (r5-verified): position p holds source chunk p ^ ((row>>1)&3) ->
// 2-way bank aliasing (free, m136). Per-wave output 128x64 (good LDS ratio).
// Frag maps: A row=l16(+16*mi+128*wm), k-chunk=qr; C/D col=l16, row=qr*4+reg.

#define GEMM_PRE32()                                                            \
  const int tid = threadIdx.x;                                                  \
  const int lane = tid & 63;                                                    \
  const int wave = tid >> 6;                                                    \
  const int wm = wave >> 2, wn = wave & 3;                                      \
  const int qr = lane >> 4, l16 = lane & 15;                                    \
  uint32_t aOff[8], bOff[4];                                                    \
  _Pragma("unroll")                                                             \
  for (int mi = 0; mi < 8; ++mi) {                                              \
    int r = wm * 128 + mi * 16 + l16;                                           \
    aOff[mi] = r * 64 + ((qr ^ ((r >> 1) & 3)) * 16);                           \
  }                                                                             \
  _Pragma("unroll")                                                             \
  for (int ni = 0; ni < 4; ++ni) {                                              \
    int r = wn * 64 + ni * 16 + l16;                                            \
    bOff[ni] = 16384 + r * 64 + ((qr ^ ((r >> 1) & 3)) * 16);                   \
  }

#define STAGE32(P, KT) {                                                        \
  const char* _d = lds + (P) * 32768 + tid * 16;                                \
  gload_lds16(aP[0] + (size_t)(KT) * BK, _d);                                   \
  gload_lds16(aP[1] + (size_t)(KT) * BK, _d + 8192);                            \
  gload_lds16(bP[0] + (size_t)(KT) * BK, _d + 16384);                           \
  gload_lds16(bP[1] + (size_t)(KT) * BK, _d + 24576); }

#define COMPUTE32(P) {                                                          \
  const char* _p = lds + (P) * 32768;                                           \
  bf16x8 af[8], bfr[4];                                                         \
  _Pragma("unroll")                                                             \
  for (int mi = 0; mi < 8; ++mi) af[mi] = *(const bf16x8*)(_p + aOff[mi]);      \
  _Pragma("unroll")                                                             \
  for (int ni = 0; ni < 4; ++ni) bfr[ni] = *(const bf16x8*)(_p + bOff[ni]);     \
  __builtin_amdgcn_s_setprio(1);                                                \
  _Pragma("unroll")                                                             \
  for (int mi = 0; mi < 8; ++mi)                                                \
  _Pragma("unroll")                                                             \
  for (int ni = 0; ni < 4; ++ni)                                                \
    acc[mi][ni] = __builtin_amdgcn_mfma_f32_16x16x32_bf16(                      \
        af[mi], bfr[ni], acc[mi][ni], 0, 0, 0);                                 \
  __builtin_amdgcn_s_setprio(0); }

#define KLOOP32(NT)                                                             \
  STAGE32(0, 0);                                                                \
  __syncthreads();                                                              \
  for (int t = 0; t < (NT) - 1; ++t) {                                          \
    STAGE32((t + 1) & 1, t + 1);                                                \
    COMPUTE32(t & 1);                                                           \
    __syncthreads();                                                            \
  }                                                                             \
  COMPUTE32(((NT) - 1) & 1);

// Stage-source helper: slot s (0..1023) -> row=s>>2, chunk cs=(s&3)^((row>>1)&3)
#define STAGE_SRC(ROWEXPR, BASE, LDK)                                           \
  _Pragma("unroll")                                                             \
  for (int j = 0; j < 2; ++j) {                                                 \
    int s = j * 512 + tid;                                                      \
    int rl = s >> 2, cs = (s & 3) ^ ((rl >> 1) & 3);                            \
    (void)0;                                                                    \
  }

// ---------------- GEMM1: Hb = gelu(gather(Xb) @ W1t^T + b1) ----------------
__global__ __launch_bounds__(512, 4) void gemm1_kernel(
    const bf16_t* __restrict__ Xb, const bf16_t* __restrict__ W1t,
    const float* __restrict__ b1, const int* __restrict__ ptok,
    const int* __restrict__ meta, bf16_t* __restrict__ Hb) {
  __shared__ __align__(16) char lds[65536];
  GEMM_PRE32();
  // banded 2D XCD mapping (r14): XCD owns 17-mt strip, walks 4 nt-bands
  int b = blockIdx.x;                       // 2176 blocks
  int xcd = b & 7, w = b >> 3;
  int band = w / 68, r0i = w % 68;
  const int mt = xcd * 17 + (r0i >> 2);
  const int nt = band * 4 + (r0i & 3);
  const int row0 = mt * 256;
  const int* seg = meta + 16;
  int e = 0;
#pragma unroll
  for (int k = 1; k < NE; ++k) if (row0 >= seg[k]) e = k;
  if (row0 - seg[e] >= meta[e]) return;

  const bf16_t* aP[2];
  const bf16_t* bP[2];
  const bf16_t* wb = W1t + (size_t)e * HID * DIM;
#pragma unroll
  for (int j = 0; j < 2; ++j) {
    int s = j * 512 + tid;
    int rl = s >> 2, cs = (s & 3) ^ ((rl >> 1) & 3);
    int tok = ptok[row0 + rl];
    if (tok < 0) tok = 0;
    aP[j] = Xb + (size_t)tok * DIM + cs * 8;
    bP[j] = wb + (size_t)(nt * 256 + rl) * DIM + cs * 8;
  }

  f32x4 acc[8][4] = {};
  KLOOP32(DIM / BK);

  // epilogue: + b1, exact gelu, bf16 store
#pragma unroll
  for (int ni = 0; ni < 4; ++ni) {
    int col = nt * 256 + wn * 64 + ni * 16 + l16;
    float bv = b1[e * HID + col];
#pragma unroll
    for (int mi = 0; mi < 8; ++mi) {
      int rb = row0 + wm * 128 + mi * 16 + qr * 4;
#pragma unroll
      for (int j = 0; j < 4; ++j) {
        float v = acc[mi][ni][j] + bv;
        float g2 = 0.5f * v * (1.0f + erff(v * 0.70710678118654752f));
        Hb[(size_t)(rb + j) * HID + col] = (bf16_t)g2;
      }
    }
  }
}

// ---------------- GEMM2: out[tok] += w * (Hb @ W2t^T + b2) ----------------
__global__ __launch_bounds__(512, 4) void gemm2_kernel(
    const bf16_t* __restrict__ Hb, const bf16_t* __restrict__ W2t,
    const float* __restrict__ b2, const int* __restrict__ ptok,
    const float* __restrict__ pw, const int* __restrict__ meta,
    float* __restrict__ out) {
  __shared__ __align__(16) char lds[65536];
  GEMM_PRE32();
  int b = blockIdx.x;                       // 544 blocks
  int g = (b & 7) * 68 + (b >> 3);
  const int mt = g >> 2, nt = g & 3;
  const int row0 = mt * 256;
  const int* seg = meta + 16;
  int e = 0;
#pragma unroll
  for (int k = 1; k < NE; ++k) if (row0 >= seg[k]) e = k;
  if (row0 - seg[e] >= meta[e]) return;

  const bf16_t* aP[2];
  const bf16_t* bP[2];
  const bf16_t* wb = W2t + (size_t)e * DIM * HID;
#pragma unroll
  for (int j = 0; j < 2; ++j) {
    int s = j * 512 + tid;
    int rl = s >> 2, cs = (s & 3) ^ ((rl >> 1) & 3);
    aP[j] = Hb + (size_t)(row0 + rl) * HID + cs * 8;
    bP[j] = wb + (size_t)(nt * 256 + rl) * HID + cs * 8;
  }

  f32x4 acc[8][4] = {};
  KLOOP32(HID / BK);

  // epilogue: gather-combine with atomics
  float bv2[4];
#pragma unroll
  for (int ni = 0; ni < 4; ++ni)
    bv2[ni] = b2[e * DIM + nt * 256 + wn * 64 + ni * 16 + l16];

#pragma unroll
  for (int mi = 0; mi < 8; ++mi) {
    int rb = row0 + wm * 128 + mi * 16 + qr * 4;
    int tk[4]; float wv[4];
#pragma unroll
    for (int j = 0; j < 4; ++j) { tk[j] = ptok[rb + j]; wv[j] = pw[rb + j]; }
#pragma unroll
    for (int ni = 0; ni < 4; ++ni) {
      int col = nt * 256 + wn * 64 + ni * 16 + l16;
#pragma unroll
      for (int j = 0; j < 4; ++j) {
        if (tk[j] >= 0)
          atomicAdd(out + (size_t)tk[j] * DIM + col,
                    wv[j] * (acc[mi][ni][j] + bv2[ni]));
      }
    }
  }
}

extern "C" void kernel_launch(void* const* d_in, const int* in_sizes, int n_in,
                              void* d_out, int out_size, void* d_ws, size_t ws_size,
                              hipStream_t stream) {
  const float* x    = (const float*)d_in[0];
  const float* rw   = (const float*)d_in[1];
  const float* w1   = (const float*)d_in[2];
  const float* b1   = (const float*)d_in[3];
  const float* w2   = (const float*)d_in[4];
  const float* b2   = (const float*)d_in[5];
  const float* bias = (const float*)d_in[6];
  float* out    = (float*)d_out;
  float* logits = out + (size_t)T_TOK * DIM;
  char* ws = (char*)d_ws;

  // big layout: separate W1t/W2t -> 5 launches
  const size_t B_XB  = 0;
  const size_t B_W1T = 33554432;
  const size_t B_W2T = 100663296;
  const size_t B_HB  = 167772160;
  const size_t B_PT  = 452984832;
  const size_t B_PW  = 453124096;
  const size_t B_TE  = 453263360;
  const size_t B_TW  = 453394432;
  const size_t B_MT  = 453525504;
  const size_t NEED_BIG = B_MT + 128;

  // fallback layout: W1t/W2t overlay -> 6 launches
  const size_t F_XB = 0;
  const size_t F_WT = 33554432;
  const size_t F_HB = 100663296;
  const size_t F_PT = 385875968;
  const size_t F_PW = 386015232;
  const size_t F_TE = 386154496;
  const size_t F_TW = 386285568;
  const size_t F_MT = 386416640;
  const size_t NEED_FB = F_MT + 128;

  if (ws_size >= NEED_BIG) {
    bf16_t* Xb  = (bf16_t*)(ws + B_XB);
    bf16_t* W1t = (bf16_t*)(ws + B_W1T);
    bf16_t* W2t = (bf16_t*)(ws + B_W2T);
    bf16_t* Hb  = (bf16_t*)(ws + B_HB);
    int*    ptok= (int*)  (ws + B_PT);
    float*  pwv = (float*)(ws + B_PW);
    int*    te  = (int*)  (ws + B_TE);
    float*  tw  = (float*)(ws + B_TW);
    int*    meta= (int*)  (ws + B_MT);

    router_kernel<<<T_TOK / 4, 256, 0, stream>>>(x, rw, logits, meta, te, tw,
                                                 Xb, ptok, out, bias);
    scatter_kernel<<<T_TOK / 256, 256, 0, stream>>>(te, tw, meta, ptok, pwv);
    transpose_both_kernel<<<4096, 256, 0, stream>>>(w1, w2, W1t, W2t);
    gemm1_kernel<<<2176, 512, 0, stream>>>(Xb, W1t, b1, ptok, meta, Hb);
    gemm2_kernel<<<544, 512, 0, stream>>>(Hb, W2t, b2, ptok, pwv, meta, out);
  } else {
    if (ws_size < NEED_FB) return;
    bf16_t* Xb  = (bf16_t*)(ws + F_XB);
    bf16_t* Wt  = (bf16_t*)(ws + F_WT);
    bf16_t* Hb  = (bf16_t*)(ws + F_HB);
    int*    ptok= (int*)  (ws + F_PT);
    float*  pwv = (float*)(ws + F_PW);
    int*    te  = (int*)  (ws + F_TE);
    float*  tw  = (float*)(ws + F_TW);
    int*    meta= (int*)  (ws + F_MT);

    router_kernel<<<T_TOK / 4, 256, 0, stream>>>(x, rw, logits, meta, te, tw,
                                                 Xb, ptok, out, bias);
    scatter_kernel<<<T_TOK / 256, 256, 0, stream>>>(te, tw, meta, ptok, pwv);
    transpose_cvt_kernel<<<dim3(HID / 256, DIM / 64, NE), 256, 0, stream>>>(w1, Wt, DIM, HID);
    gemm1_kernel<<<2176, 512, 0, stream>>>(Xb, Wt, b1, ptok, meta, Hb);
    transpose_cvt_kernel<<<dim3(DIM / 256, HID / 64, NE), 256, 0, stream>>>(w2, Wt, HID, DIM);
    gemm2_kernel<<<544, 512, 0, stream>>>(Hb, Wt, b2, ptok, pwv, meta, out);
  }
}

// Round 16
// 1009.546 us; speedup vs baseline: 6.8251x; 6.8251x over previous
//
#include <hip/hip_runtime.h>
#include <hip/hip_bf16.h>
#include <cstdint>
#include <cstddef>

#define T_TOK 16384
#define DIM   1024
#define HID   4096
#define NE    8
#define NSLOT 34816   /* 32768 + 8*256 max padded slots (256-aligned segments) */
#define BK 64

typedef __bf16 bf16_t;
typedef __bf16 bf16x8 __attribute__((ext_vector_type(8)));
typedef float  f32x4  __attribute__((ext_vector_type(4)));

__device__ __forceinline__ void gload_lds16(const void* g, const void* l) {
  __builtin_amdgcn_global_load_lds(
      (const __attribute__((address_space(1))) uint32_t*)(uintptr_t)g,
      (__attribute__((address_space(3))) uint32_t*)(uint32_t)(uintptr_t)l,
      16, 0, 0);
}

// meta layout (ints): [0..7]=counts, [8..15]=cursor, [16..23]=seg_base

// router + fused: f32->bf16 x conversion, ptok=-1 init, out=bias init,
// cursor zeroing. All consumed only by LATER kernels (boundary-ordered).
__global__ __launch_bounds__(256) void router_kernel(
    const float* __restrict__ x, const float* __restrict__ rw,
    float* __restrict__ logits, int* __restrict__ meta,
    int* __restrict__ te, float* __restrict__ tw, bf16_t* __restrict__ Xb,
    int* __restrict__ ptok, float* __restrict__ out,
    const float* __restrict__ bias) {
  int gi = blockIdx.x * 256 + threadIdx.x;
  if (gi < NSLOT) ptok[gi] = -1;
  if (gi < 8) meta[8 + gi] = 0;
  const int n4 = T_TOK * DIM / 4;
  for (int i = gi; i < n4; i += gridDim.x * 256) {
    ((float4*)out)[i] = ((const float4*)bias)[i & 255];
  }

  const int lane = threadIdx.x & 63;
  const int t = blockIdx.x * 4 + (threadIdx.x >> 6);
  const float* xr = x + (size_t)t * DIM;
  float acc[NE] = {0.f,0.f,0.f,0.f,0.f,0.f,0.f,0.f};
#pragma unroll
  for (int j = 0; j < 2; ++j) {
    int d0 = j * 512 + lane * 8;
    float4 a = *(const float4*)(xr + d0);
    float4 b = *(const float4*)(xr + d0 + 4);
    bf16x8 o = { (bf16_t)a.x, (bf16_t)a.y, (bf16_t)a.z, (bf16_t)a.w,
                 (bf16_t)b.x, (bf16_t)b.y, (bf16_t)b.z, (bf16_t)b.w };
    *(bf16x8*)(Xb + (size_t)t * DIM + d0) = o;
    float xs[8] = {a.x, a.y, a.z, a.w, b.x, b.y, b.z, b.w};
#pragma unroll
    for (int k = 0; k < 8; ++k) {
      float4 wa = *(const float4*)(rw + (size_t)(d0 + k) * NE);
      float4 wb = *(const float4*)(rw + (size_t)(d0 + k) * NE + 4);
      acc[0] += xs[k] * wa.x; acc[1] += xs[k] * wa.y;
      acc[2] += xs[k] * wa.z; acc[3] += xs[k] * wa.w;
      acc[4] += xs[k] * wb.x; acc[5] += xs[k] * wb.y;
      acc[6] += xs[k] * wb.z; acc[7] += xs[k] * wb.w;
    }
  }
#pragma unroll
  for (int off = 32; off; off >>= 1) {
#pragma unroll
    for (int e = 0; e < NE; ++e) acc[e] += __shfl_down(acc[e], off);
  }
  if (lane == 0) {
    float m = acc[0];
#pragma unroll
    for (int e = 1; e < NE; ++e) m = fmaxf(m, acc[e]);
    float p[NE]; float s = 0.f;
#pragma unroll
    for (int e = 0; e < NE; ++e) { p[e] = expf(acc[e] - m); s += p[e]; }
    float inv = 1.0f / s;
    int e0 = 0;
#pragma unroll
    for (int e = 1; e < NE; ++e) if (p[e] > p[e0]) e0 = e;
    int e1 = (e0 == 0) ? 1 : 0;
#pragma unroll
    for (int e = 0; e < NE; ++e) if (e != e0 && p[e] > p[e1]) e1 = e;
#pragma unroll
    for (int e = 0; e < NE; ++e) logits[(size_t)t * NE + e] = acc[e];
    te[2 * t]     = e0;  te[2 * t + 1] = e1;
    tw[2 * t]     = p[e0] * inv;
    tw[2 * t + 1] = p[e1] * inv;
  }
}

// scatter: each block independently recomputes global counts (compare-accum
// histogram over te), derives 256-aligned segments, then places its own 512
// entries via LDS-aggregated cursor atomics (8 global atomics/block).
__global__ __launch_bounds__(256) void scatter_kernel(
    const int* __restrict__ te, const float* __restrict__ tw,
    int* __restrict__ meta, int* __restrict__ ptok, float* __restrict__ pw) {
  __shared__ int gcnt[8], sseg[8], gbase[8], lcnt[8];
  const int t0 = threadIdx.x;
  if (t0 < 8) { gcnt[t0] = 0; lcnt[t0] = 0; }
  __syncthreads();
  int h0=0,h1=0,h2=0,h3=0,h4=0,h5=0,h6=0,h7=0;
  for (int i = t0; i < 2 * T_TOK; i += 256) {
    int e = te[i];
    h0 += (e == 0); h1 += (e == 1); h2 += (e == 2); h3 += (e == 3);
    h4 += (e == 4); h5 += (e == 5); h6 += (e == 6); h7 += (e == 7);
  }
  atomicAdd(&gcnt[0], h0); atomicAdd(&gcnt[1], h1);
  atomicAdd(&gcnt[2], h2); atomicAdd(&gcnt[3], h3);
  atomicAdd(&gcnt[4], h4); atomicAdd(&gcnt[5], h5);
  atomicAdd(&gcnt[6], h6); atomicAdd(&gcnt[7], h7);
  __syncthreads();
  if (t0 < 8) {
    int s2 = 0;
#pragma unroll
    for (int e2 = 0; e2 < 8; ++e2) {
      int p = (gcnt[e2] + 255) & ~255;
      s2 += (e2 < t0) ? p : 0;
    }
    sseg[t0] = s2;
    if (blockIdx.x == 0) { meta[t0] = gcnt[t0]; meta[16 + t0] = s2; }
  }
  // local placement (order within a segment is irrelevant)
  int t = blockIdx.x * 256 + t0;
  int e0 = te[2 * t], e1 = te[2 * t + 1];
  int lp0 = atomicAdd(&lcnt[e0], 1);
  int lp1 = atomicAdd(&lcnt[e1], 1);
  __syncthreads();
  if (t0 < 8) gbase[t0] = atomicAdd(&meta[8 + t0], lcnt[t0]);
  __syncthreads();
  int pos0 = sseg[e0] + gbase[e0] + lp0;
  int pos1 = sseg[e1] + gbase[e1] + lp1;
  ptok[pos0] = t;  pw[pos0] = tw[2 * t];
  ptok[pos1] = t;  pw[pos1] = tw[2 * t + 1];
}

// LDS-free register transpose tile: src float RxC -> dst bf16 CxR (r12-verified)
__device__ __forceinline__ void tr_tile(const float* __restrict__ s,
                                        bf16_t* __restrict__ d,
                                        int R, int C, int c0, int r0) {
  const int tr = threadIdx.x & 7, tc = threadIdx.x >> 3;
  bf16x8 rows[8];
#pragma unroll
  for (int p = 0; p < 8; ++p) {
    const float* rp = s + (size_t)(r0 + 8 * tr + p) * C + c0 + 8 * tc;
    float4 a = *(const float4*)rp;
    float4 b = *(const float4*)(rp + 4);
    bf16x8 v = { (bf16_t)a.x, (bf16_t)a.y, (bf16_t)a.z, (bf16_t)a.w,
                 (bf16_t)b.x, (bf16_t)b.y, (bf16_t)b.z, (bf16_t)b.w };
    rows[p] = v;
  }
#pragma unroll
  for (int q = 0; q < 8; ++q) {
    bf16x8 o = { rows[0][q], rows[1][q], rows[2][q], rows[3][q],
                 rows[4][q], rows[5][q], rows[6][q], rows[7][q] };
    *(bf16x8*)(d + (size_t)(c0 + 8 * tc + q) * R + r0 + 8 * tr) = o;
  }
}

// big-ws path: both weights transposed in ONE launch (separate buffers)
__global__ __launch_bounds__(256) void transpose_both_kernel(
    const float* __restrict__ w1, const float* __restrict__ w2,
    bf16_t* __restrict__ W1t, bf16_t* __restrict__ W2t) {
  int b = blockIdx.x;
  if (b < 2048) {
    int e = b >> 8, rem = b & 255;
    tr_tile(w1 + (size_t)e * DIM * HID, W1t + (size_t)e * DIM * HID,
            DIM, HID, (rem & 15) * 256, (rem >> 4) * 64);
  } else {
    b -= 2048;
    int e = b >> 8, rem = b & 255;
    tr_tile(w2 + (size_t)e * DIM * HID, W2t + (size_t)e * DIM * HID,
            HID, DIM, (rem & 3) * 256, (rem >> 2) * 64);
  }
}

// fallback path: single-matrix transpose (r12)
__global__ __launch_bounds__(256) void transpose_cvt_kernel(
    const float* __restrict__ src, bf16_t* __restrict__ dst, int R, int C) {
  int e = blockIdx.z;
  tr_tile(src + (size_t)e * R * C, dst + (size_t)e * R * C,
          R, C, blockIdx.x * 256, blockIdx.y * 64);
}

// ======= 256x256 8-wave, 8-phase GEMM (r10/r13 schedule, byte-identical) =======
#define GEMM_PRE()                                                              \
  const int tid = threadIdx.x;                                                  \
  const int lane = tid & 63;                                                    \
  const int wave = tid >> 6;                                                    \
  const int wm = wave >> 2, wn = wave & 3;                                      \
  const int qr = lane >> 4, l16 = lane & 15;                                    \
  const uint32_t aRd0 = (wm * 64 + l16) * 128 + ((qr ^ (l16 & 7)) * 16);        \
  const uint32_t aRd1 = (wm * 64 + l16) * 128 + (((4 + qr) ^ (l16 & 7)) * 16);  \
  const uint32_t bRd0 = (wn * 32 + l16) * 128 + ((qr ^ (l16 & 7)) * 16);        \
  const uint32_t bRd1 = (wn * 32 + l16) * 128 + (((4 + qr) ^ (l16 & 7)) * 16);

#define WAIT_LGKM(N) asm volatile("s_waitcnt lgkmcnt(" #N ")" ::: "memory")
#define WAIT_VM(N)   asm volatile("s_waitcnt vmcnt(" #N ")" ::: "memory")
#define BAR()        __builtin_amdgcn_s_barrier()

#define STAGE_AH(P, H, KT) {                                                    \
  const char* _d = lds + ((P) * 2 + (H)) * 16384 + tid * 16;                    \
  gload_lds16(aSrc[H][0] + (size_t)(KT) * BK, _d);                              \
  gload_lds16(aSrc[H][1] + (size_t)(KT) * BK, _d + 8192); }

#define STAGE_BH(P, H, KT) {                                                    \
  const char* _d = lds + 65536 + ((P) * 2 + (H)) * 16384 + tid * 16;            \
  gload_lds16(bSrc[H][0] + (size_t)(KT) * BK, _d);                              \
  gload_lds16(bSrc[H][1] + (size_t)(KT) * BK, _d + 8192); }

#define LOAD_AH(P, H, AF) {                                                     \
  const char* _p = lds + ((P) * 2 + (H)) * 16384;                               \
  _Pragma("unroll")                                                             \
  for (int mi = 0; mi < 4; ++mi) {                                              \
    AF[mi][0] = *(const bf16x8*)(_p + aRd0 + mi * 2048);                        \
    AF[mi][1] = *(const bf16x8*)(_p + aRd1 + mi * 2048); } }

#define LOAD_BH(P, H, BF) {                                                     \
  const char* _p = lds + 65536 + ((P) * 2 + (H)) * 16384;                       \
  _Pragma("unroll")                                                             \
  for (int ni = 0; ni < 2; ++ni) {                                              \
    BF[ni][0] = *(const bf16x8*)(_p + bRd0 + ni * 2048);                        \
    BF[ni][1] = *(const bf16x8*)(_p + bRd1 + ni * 2048); } }

#define MFMA_Q(AH, BH, AF, BF)                                                  \
  __builtin_amdgcn_s_setprio(1);                                                \
  _Pragma("unroll")                                                             \
  for (int mi = 0; mi < 4; ++mi)                                                \
  _Pragma("unroll")                                                             \
  for (int ni = 0; ni < 2; ++ni) {                                              \
    acc[AH][BH][mi][ni] = __builtin_amdgcn_mfma_f32_16x16x32_bf16(              \
        AF[mi][0], BF[ni][0], acc[AH][BH][mi][ni], 0, 0, 0);                    \
    acc[AH][BH][mi][ni] = __builtin_amdgcn_mfma_f32_16x16x32_bf16(              \
        AF[mi][1], BF[ni][1], acc[AH][BH][mi][ni], 0, 0, 0);                    \
  }                                                                             \
  __builtin_amdgcn_s_setprio(0);

#define ITER8(T, NT)                                                            \
  {                                                                             \
    const int ktO1 = ((T) + 1 < (NT)) ? (T) + 1 : (NT) - 1;                     \
    const int ktE  = ((T) + 2 < (NT)) ? (T) + 2 : (NT) - 1;                     \
    const int ktO  = ((T) + 3 < (NT)) ? (T) + 3 : (NT) - 1;                     \
    STAGE_BH(1, 1, ktO1);                                                       \
    LOAD_AH(0, 0, afA); LOAD_BH(0, 0, bf0);                                     \
    WAIT_LGKM(8); BAR(); WAIT_LGKM(0);                                          \
    MFMA_Q(0, 0, afA, bf0); BAR();                                              \
    STAGE_AH(0, 0, ktE);                                                        \
    LOAD_AH(0, 1, afB);                                                         \
    BAR(); WAIT_LGKM(0);                                                        \
    MFMA_Q(1, 0, afB, bf0); BAR();                                              \
    STAGE_BH(0, 0, ktE);                                                        \
    LOAD_BH(0, 1, bf1);                                                         \
    BAR(); WAIT_LGKM(0);                                                        \
    MFMA_Q(1, 1, afB, bf1); BAR();                                              \
    STAGE_AH(0, 1, ktE);                                                        \
    BAR();                                                                      \
    MFMA_Q(0, 1, afA, bf1);                                                     \
    WAIT_VM(6); BAR();                                                          \
    STAGE_BH(0, 1, ktE);                                                        \
    LOAD_AH(1, 0, afA); LOAD_BH(1, 0, bf0);                                     \
    WAIT_LGKM(8); BAR(); WAIT_LGKM(0);                                          \
    MFMA_Q(0, 0, afA, bf0); BAR();                                              \
    STAGE_AH(1, 0, ktO);                                                        \
    LOAD_AH(1, 1, afB);                                                         \
    BAR(); WAIT_LGKM(0);                                                        \
    MFMA_Q(1, 0, afB, bf0); BAR();                                              \
    STAGE_BH(1, 0, ktO);                                                        \
    LOAD_BH(1, 1, bf1);                                                         \
    BAR(); WAIT_LGKM(0);                                                        \
    MFMA_Q(1, 1, afB, bf1); BAR();                                              \
    STAGE_AH(1, 1, ktO);                                                        \
    BAR();                                                                      \
    MFMA_Q(0, 1, afA, bf1);                                                     \
    WAIT_VM(6); BAR();                                                          \
  }

#define KLOOP8(NT)                                                              \
  {                                                                             \
    const int k1 = 1 < (NT) ? 1 : 0;                                            \
    STAGE_AH(0, 0, 0); STAGE_BH(0, 0, 0); STAGE_AH(0, 1, 0); STAGE_BH(0, 1, 0); \
    STAGE_AH(1, 0, k1); STAGE_BH(1, 0, k1); STAGE_AH(1, 1, k1);                 \
    WAIT_VM(6); BAR();                                                          \
  }                                                                             \
  for (int t = 0; t < (NT); t += 2) ITER8(t, NT)

// ---------------- GEMM1: Hb = gelu(gather(Xb) @ W1t^T + b1) ----------------
__global__ __launch_bounds__(512, 2) void gemm1_kernel(
    const bf16_t* __restrict__ Xb, const bf16_t* __restrict__ W1t,
    const float* __restrict__ b1, const int* __restrict__ ptok,
    const int* __restrict__ meta, bf16_t* __restrict__ Hb) {
  __shared__ __align__(16) char lds[131072];
  GEMM_PRE();
  // banded 2D XCD mapping: each XCD owns a 17-mt strip, walks it in 4 nt-bands.
  int b = blockIdx.x;                       // 2176 blocks
  int xcd = b & 7, w = b >> 3;              // w in [0,272)
  int band = w / 68, r0i = w % 68;
  const int mt = xcd * 17 + (r0i >> 2);
  const int nt = band * 4 + (r0i & 3);
  const int row0 = mt * 256;
  const int* seg = meta + 16;
  int e = 0;
#pragma unroll
  for (int k = 1; k < NE; ++k) if (row0 >= seg[k]) e = k;
  if (row0 - seg[e] >= meta[e]) return;

  const bf16_t* aSrc[2][2];
  const bf16_t* bSrc[2][2];
#pragma unroll
  for (int h = 0; h < 2; ++h)
#pragma unroll
    for (int j = 0; j < 2; ++j) {
      int idx = j * 512 + tid;
      int rl = idx >> 3, c = idx & 7;
      int cs = c ^ (rl & 7);
      int tok = ptok[row0 + h * 128 + rl];
      if (tok < 0) tok = 0;
      aSrc[h][j] = Xb + (size_t)tok * DIM + cs * 8;
      int brow = nt * 256 + h * 128 + rl;
      bSrc[h][j] = W1t + (size_t)e * HID * DIM + (size_t)brow * DIM + cs * 8;
    }

  f32x4 acc[2][2][4][2] = {};
  bf16x8 afA[4][2], afB[4][2], bf0[2][2], bf1[2][2];
  KLOOP8(DIM / BK);

#pragma unroll
  for (int BH_ = 0; BH_ < 2; ++BH_)
#pragma unroll
  for (int ni = 0; ni < 2; ++ni) {
    int col = nt * 256 + BH_ * 128 + wn * 32 + ni * 16 + l16;
    float bv = b1[e * HID + col];
#pragma unroll
    for (int AH_ = 0; AH_ < 2; ++AH_)
#pragma unroll
    for (int mi = 0; mi < 4; ++mi) {
      int r = row0 + AH_ * 128 + wm * 64 + mi * 16 + qr * 4;
#pragma unroll
      for (int j = 0; j < 4; ++j) {
        float v = acc[AH_][BH_][mi][ni][j] + bv;
        float g2 = 0.5f * v * (1.0f + erff(v * 0.70710678118654752f));
        Hb[(size_t)(r + j) * HID + col] = (bf16_t)g2;
      }
    }
  }
}

// ---------------- GEMM2: out[tok] += w * (Hb @ W2t^T + b2) ----------------
__global__ __launch_bounds__(512, 2) void gemm2_kernel(
    const bf16_t* __restrict__ Hb, const bf16_t* __restrict__ W2t,
    const float* __restrict__ b2, const int* __restrict__ ptok,
    const float* __restrict__ pw, const int* __restrict__ meta,
    float* __restrict__ out) {
  __shared__ __align__(16) char lds[131072];
  GEMM_PRE();
  int b = blockIdx.x;                       // 544 blocks
  int g = (b & 7) * 68 + (b >> 3);
  const int mt = g >> 2, nt = g & 3;
  const int row0 = mt * 256;
  const int* seg = meta + 16;
  int e = 0;
#pragma unroll
  for (int k = 1; k < NE; ++k) if (row0 >= seg[k]) e = k;
  if (row0 - seg[e] >= meta[e]) return;

  const bf16_t* aSrc[2][2];
  const bf16_t* bSrc[2][2];
#pragma unroll
  for (int h = 0; h < 2; ++h)
#pragma unroll
    for (int j = 0; j < 2; ++j) {
      int idx = j * 512 + tid;
      int rl = idx >> 3, c = idx & 7;
      int cs = c ^ (rl & 7);
      aSrc[h][j] = Hb + (size_t)(row0 + h * 128 + rl) * HID + cs * 8;
      int brow = nt * 256 + h * 128 + rl;
      bSrc[h][j] = W2t + (size_t)e * DIM * HID + (size_t)brow * HID + cs * 8;
    }

  f32x4 acc[2][2][4][2] = {};
  bf16x8 afA[4][2], afB[4][2], bf0[2][2], bf1[2][2];
  KLOOP8(HID / BK);

  float bv2[2][2];
#pragma unroll
  for (int BH_ = 0; BH_ < 2; ++BH_)
#pragma unroll
  for (int ni = 0; ni < 2; ++ni)
    bv2[BH_][ni] = b2[e * DIM + nt * 256 + BH_ * 128 + wn * 32 + ni * 16 + l16];

#pragma unroll
  for (int AH_ = 0; AH_ < 2; ++AH_)
#pragma unroll
  for (int mi = 0; mi < 4; ++mi) {
    int r = row0 + AH_ * 128 + wm * 64 + mi * 16 + qr * 4;
    int tk[4]; float wv[4];
#pragma unroll
    for (int j = 0; j < 4; ++j) { tk[j] = ptok[r + j]; wv[j] = pw[r + j]; }
#pragma unroll
    for (int BH_ = 0; BH_ < 2; ++BH_)
#pragma unroll
    for (int ni = 0; ni < 2; ++ni) {
      int col = nt * 256 + BH_ * 128 + wn * 32 + ni * 16 + l16;
#pragma unroll
      for (int j = 0; j < 4; ++j) {
        if (tk[j] >= 0)
          atomicAdd(out + (size_t)tk[j] * DIM + col,
                    wv[j] * (acc[AH_][BH_][mi][ni][j] + bv2[BH_][ni]));
      }
    }
  }
}

extern "C" void kernel_launch(void* const* d_in, const int* in_sizes, int n_in,
                              void* d_out, int out_size, void* d_ws, size_t ws_size,
                              hipStream_t stream) {
  const float* x    = (const float*)d_in[0];
  const float* rw   = (const float*)d_in[1];
  const float* w1   = (const float*)d_in[2];
  const float* b1   = (const float*)d_in[3];
  const float* w2   = (const float*)d_in[4];
  const float* b2   = (const float*)d_in[5];
  const float* bias = (const float*)d_in[6];
  float* out    = (float*)d_out;
  float* logits = out + (size_t)T_TOK * DIM;
  char* ws = (char*)d_ws;

  // big layout: separate W1t/W2t (no overlay) -> 5 launches
  const size_t B_XB  = 0;                    // bf16 [T][D]       33,554,432
  const size_t B_W1T = 33554432;             // bf16 [E][H][D]    67,108,864
  const size_t B_W2T = 100663296;            // bf16 [E][D][H]    67,108,864
  const size_t B_HB  = 167772160;            // bf16 [NSLOT][H]  285,212,672
  const size_t B_PT  = 452984832;            // int  [NSLOT]
  const size_t B_PW  = 453124096;            // f32  [NSLOT]
  const size_t B_TE  = 453263360;            // int  [T*2]
  const size_t B_TW  = 453394432;            // f32  [T*2]
  const size_t B_MT  = 453525504;            // int  [32]
  const size_t NEED_BIG = B_MT + 128;

  // fallback layout (r12, proven): W1t/W2t overlay -> 6 launches
  const size_t F_XB = 0;
  const size_t F_WT = 33554432;
  const size_t F_HB = 100663296;
  const size_t F_PT = 385875968;
  const size_t F_PW = 386015232;
  const size_t F_TE = 386154496;
  const size_t F_TW = 386285568;
  const size_t F_MT = 386416640;
  const size_t NEED_FB = F_MT + 128;

  if (ws_size >= NEED_BIG) {
    bf16_t* Xb  = (bf16_t*)(ws + B_XB);
    bf16_t* W1t = (bf16_t*)(ws + B_W1T);
    bf16_t* W2t = (bf16_t*)(ws + B_W2T);
    bf16_t* Hb  = (bf16_t*)(ws + B_HB);
    int*    ptok= (int*)  (ws + B_PT);
    float*  pwv = (float*)(ws + B_PW);
    int*    te  = (int*)  (ws + B_TE);
    float*  tw  = (float*)(ws + B_TW);
    int*    meta= (int*)  (ws + B_MT);

    router_kernel<<<T_TOK / 4, 256, 0, stream>>>(x, rw, logits, meta, te, tw,
                                                 Xb, ptok, out, bias);
    scatter_kernel<<<T_TOK / 256, 256, 0, stream>>>(te, tw, meta, ptok, pwv);
    transpose_both_kernel<<<4096, 256, 0, stream>>>(w1, w2, W1t, W2t);
    gemm1_kernel<<<2176, 512, 0, stream>>>(Xb, W1t, b1, ptok, meta, Hb);
    gemm2_kernel<<<544, 512, 0, stream>>>(Hb, W2t, b2, ptok, pwv, meta, out);
  } else {
    if (ws_size < NEED_FB) return;
    bf16_t* Xb  = (bf16_t*)(ws + F_XB);
    bf16_t* Wt  = (bf16_t*)(ws + F_WT);
    bf16_t* Hb  = (bf16_t*)(ws + F_HB);
    int*    ptok= (int*)  (ws + F_PT);
    float*  pwv = (float*)(ws + F_PW);
    int*    te  = (int*)  (ws + F_TE);
    float*  tw  = (float*)(ws + F_TW);
    int*    meta= (int*)  (ws + F_MT);

    router_kernel<<<T_TOK / 4, 256, 0, stream>>>(x, rw, logits, meta, te, tw,
                                                 Xb, ptok, out, bias);
    scatter_kernel<<<T_TOK / 256, 256, 0, stream>>>(te, tw, meta, ptok, pwv);
    transpose_cvt_kernel<<<dim3(HID / 256, DIM / 64, NE), 256, 0, stream>>>(w1, Wt, DIM, HID);
    gemm1_kernel<<<2176, 512, 0, stream>>>(Xb, Wt, b1, ptok, meta, Hb);
    transpose_cvt_kernel<<<dim3(DIM / 256, HID / 64, NE), 256, 0, stream>>>(w2, Wt, HID, DIM);
    gemm2_kernel<<<544, 512, 0, stream>>>(Hb, Wt, b2, ptok, pwv, meta, out);
  }
}